// Round 4
// baseline (66.277 us; speedup 1.0000x reference)
//
#include <hip/hip_runtime.h>

// BiliSample fused: bilinear-sample BEV features + 1x1 conv (GEMM) + bias.
// img_feat (2,64,32,64) f32, pix_T_cam (2,3,3) f32, conv_w (128,512) f32,
// conv_b (128,) f32 -> out (2,128,200,200) f32.
//
//  prep:  imgT[b][y][x][c] = bf16(img[b][c][y][x])   (c contiguous)
//         Wp[o][k'=y*64+c] = bf16(conv_w[o][c*8+y])  (k-permuted)
//  main (persistent, 512 blocks = 2/CU, 64-n tiles, 80 KiB LDS):
//    preload: per-wave Wp A-fragments (32 x bf16x8 = 128 VGPR) + bias, ONCE
//    per tile: A: 512 (n,y) projections -> offsets+weights LDS
//              B: 8-lane groups sample 64 ch/corner (uint4), cvt_pk_bf16,
//                 F[64][512] bf16 LDS, XOR-swizzled
//              C: 4 waves x (2 o-tiles x 4 n-tiles) mfma_f32_16x16x32_bf16,
//                 A from registers, B from LDS; acc seeded with bias.

#define NPOS 40000

typedef short bf16x8 __attribute__((ext_vector_type(8)));
typedef float f32x4  __attribute__((ext_vector_type(4)));

__device__ __forceinline__ unsigned rne16(float f) {
    unsigned u = __float_as_uint(f);
    return (u + 0x7fffu + ((u >> 16) & 1u)) >> 16;
}
__device__ __forceinline__ float lo16(unsigned u) { return __uint_as_float(u << 16); }
__device__ __forceinline__ float hi16(unsigned u) { return __uint_as_float(u & 0xffff0000u); }
__device__ __forceinline__ unsigned cvtpk(float lo, float hi) {
    unsigned r;
    asm("v_cvt_pk_bf16_f32 %0, %1, %2" : "=v"(r) : "v"(lo), "v"(hi));
    return r;
}

// ---------------- prep: transpose img to channel-major bf16, permute W ----------------
__global__ __launch_bounds__(256)
void bili_prep(const float* __restrict__ img, const float* __restrict__ convw,
               unsigned short* __restrict__ imgT, unsigned short* __restrict__ Wp)
{
    const int i = blockIdx.x * 256 + threadIdx.x;
    if (blockIdx.x < 1024) {
        // imgT[b][y][x][c], i = ((b*32+y)*64+x)*64+c
        const int c = i & 63, x = (i >> 6) & 63, y = (i >> 12) & 31, b = i >> 17;
        imgT[i] = (unsigned short)rne16(img[((b * 64 + c) * 32 + y) * 64 + x]);
    } else {
        const int j = i - 1024 * 256;            // 0..65535
        const int k = j & 511, o = j >> 9;
        const int y = k >> 6, c = k & 63;
        Wp[j] = (unsigned short)rne16(convw[o * 512 + c * 8 + y]);
    }
}

// ---------------- main fused persistent kernel ----------------
__global__ __launch_bounds__(256, 2)
void bili_main(const uint4* __restrict__ imgTq,     // per-batch stride 16384 uint4
               const unsigned short* __restrict__ Wp,
               const float* __restrict__ pixT,
               const float* __restrict__ convb,
               float* __restrict__ out)
{
    __shared__ uint4  FsU[4096];    // F[64 n][512 k'] bf16, 64 KiB, col-XOR swizzled
    __shared__ int4   offsL[512];   // per (n,y): 4 corner uint4-offsets into imgT batch
    __shared__ float4 wtsL[512];    // per (n,y): 4 corner weights

    const int t   = threadIdx.x;
    const int wv  = t >> 6;         // wave 0..3 -> o rows wv*32..+31
    const int ln  = t & 63;
    const int l15 = ln & 15;
    const int lg  = ln >> 4;        // k-slot group

    // ---- one-time W-fragment + bias preload (lives in registers all kernel) ----
    bf16x8 wA0[16], wA1[16];
    {
        const bf16x8* ApG = (const bf16x8*)Wp;          // [128 rows][64 slots]
        const bf16x8* p0 = ApG + ((wv * 32 +      l15) * 64 + lg);
        const bf16x8* p1 = ApG + ((wv * 32 + 16 + l15) * 64 + lg);
        #pragma unroll
        for (int ks = 0; ks < 16; ++ks) {
            wA0[ks] = p0[ks * 4];
            wA1[ks] = p1[ks * 4];
        }
    }
    float bias0[4], bias1[4];
    #pragma unroll
    for (int r = 0; r < 4; ++r) {
        bias0[r] = convb[wv * 32 +      lg * 4 + r];
        bias1[r] = convb[wv * 32 + 16 + lg * 4 + r];
    }

    for (int tt = blockIdx.x; tt < 1250; tt += gridDim.x) {
        const int b  = (tt >= 625) ? 1 : 0;
        const int n0 = (tt - b * 625) * 64;

        // ---------- phase A: projections (2 per thread) ----------
        {
            const float* Kb = pixT + b * 9;
            const float K00 = Kb[0], K01 = Kb[1], K02 = Kb[2];
            const float K10 = Kb[3], K11 = Kb[4], K12 = Kb[5];
            const float K20 = Kb[6], K21 = Kb[7], K22 = Kb[8];

            #pragma unroll
            for (int r = 0; r < 2; ++r) {
                const int p    = r * 256 + t;        // 0..511
                const int nloc = p >> 3;
                const int y    = p & 7;
                const int n = n0 + nloc;
                const int z = n / 200;
                const int x = n - z * 200;

                const float pxv = (x * (1.0f / 199.0f) - 0.5f) * 80.0f;
                const float pzv = (z * (1.0f / 199.0f)) * 80.0f;
                const float pyv = (y * (1.0f / 7.0f) - 0.5f) * 6.0f;

                const float p0 = K00 * pxv + K01 * pyv + K02 * pzv;
                const float p1 = K10 * pxv + K11 * pyv + K12 * pzv;
                const float d  = K20 * pxv + K21 * pyv + K22 * pzv;
                const float dpe = d + 1e-8f;
                const float u01 = p0 / dpe / 512.0f;
                const float v01 = p1 / dpe / 256.0f;
                const float vf = (u01 >= 0.0f && u01 <= 1.0f &&
                                  v01 >= 0.0f && v01 <= 1.0f) ? 1.0f : 0.0f;

                float xp = u01 * 64.0f - 0.5f;
                xp = fminf(fmaxf(xp, -2.0f), 66.0f);
                const float x0f = floorf(xp);
                const float wx = xp - x0f;
                const int x0 = (int)x0f, x1i = x0 + 1;
                const float wx0 = (1.0f - wx) * vf * ((x0  >= 0 && x0  < 64) ? 1.0f : 0.0f);
                const float wx1 = wx          * vf * ((x1i >= 0 && x1i < 64) ? 1.0f : 0.0f);
                const int xi0 = min(max(x0, 0), 63);
                const int xi1 = min(max(x1i, 0), 63);

                float yp = v01 * 32.0f - 0.5f;
                yp = fminf(fmaxf(yp, -2.0f), 34.0f);
                const float y0f = floorf(yp);
                const float wy = yp - y0f;
                const int y0 = (int)y0f, y1i = y0 + 1;
                const float wy0 = (1.0f - wy) * ((y0  >= 0 && y0  < 32) ? 1.0f : 0.0f);
                const float wy1 = wy          * ((y1i >= 0 && y1i < 32) ? 1.0f : 0.0f);
                const int yi0 = min(max(y0, 0), 31);
                const int yi1 = min(max(y1i, 0), 31);

                wtsL[p]  = make_float4(wx0 * wy0, wx1 * wy0, wx0 * wy1, wx1 * wy1);
                offsL[p] = make_int4(((yi0 << 6) + xi0) << 3, ((yi0 << 6) + xi1) << 3,
                                     ((yi1 << 6) + xi0) << 3, ((yi1 << 6) + xi1) << 3);
            }
        }

        __syncthreads();

        // ---------- phase B: sample 64 channels per (n,y), write F to LDS ----------
        {
            const uint4* imgTb = imgTq + b * 16384;
            const int g  = t >> 3;      // 32 groups
            const int li = t & 7;       // lane-in-group: channel block c = li*8..+7

            #pragma unroll 2
            for (int it = 0; it < 16; ++it) {
                const int p    = it * 32 + g;
                const int4   off = offsL[p];
                const float4 w   = wtsL[p];
                const int nloc = p >> 3;
                const int y    = p & 7;

                float2 ac[4];
                #pragma unroll
                for (int q = 0; q < 4; ++q) ac[q] = make_float2(0.0f, 0.0f);

                uint4 v;
                #define ACC_CORNER(OFF, WW)                                    \
                    v = imgTb[(OFF) + li];                                     \
                    ac[0].x = fmaf(WW, lo16(v.x), ac[0].x);                    \
                    ac[0].y = fmaf(WW, hi16(v.x), ac[0].y);                    \
                    ac[1].x = fmaf(WW, lo16(v.y), ac[1].x);                    \
                    ac[1].y = fmaf(WW, hi16(v.y), ac[1].y);                    \
                    ac[2].x = fmaf(WW, lo16(v.z), ac[2].x);                    \
                    ac[2].y = fmaf(WW, hi16(v.z), ac[2].y);                    \
                    ac[3].x = fmaf(WW, lo16(v.w), ac[3].x);                    \
                    ac[3].y = fmaf(WW, hi16(v.w), ac[3].y);

                ACC_CORNER(off.x, w.x)
                ACC_CORNER(off.y, w.y)
                ACC_CORNER(off.z, w.z)
                ACC_CORNER(off.w, w.w)
                #undef ACC_CORNER

                uint4 pk;
                pk.x = cvtpk(ac[0].x, ac[0].y);
                pk.y = cvtpk(ac[1].x, ac[1].y);
                pk.z = cvtpk(ac[2].x, ac[2].y);
                pk.w = cvtpk(ac[3].x, ac[3].y);

                // F row nloc, k'-uint4 col (y*8+li), XOR-swizzled by (nloc&7)
                FsU[nloc * 64 + ((y * 8 + li) ^ (nloc & 7))] = pk;
            }
        }

        __syncthreads();

        // ---------- phase C: MFMA GEMM, A from registers, acc seeded w/ bias ----------
        {
            const bf16x8* FsV = (const bf16x8*)FsU;

            f32x4 acc0[4], acc1[4];
            #pragma unroll
            for (int nt = 0; nt < 4; ++nt) {
                #pragma unroll
                for (int r = 0; r < 4; ++r) {
                    acc0[nt][r] = bias0[r];
                    acc1[nt][r] = bias1[r];
                }
            }

            #pragma unroll
            for (int ks = 0; ks < 16; ++ks) {
                const int kq = ks * 4 + lg;
                #pragma unroll
                for (int nt = 0; nt < 4; ++nt) {
                    const int nn = nt * 16 + l15;
                    const bf16x8 bf = FsV[nn * 64 + (kq ^ (nn & 7))];
                    acc0[nt] = __builtin_amdgcn_mfma_f32_16x16x32_bf16(wA0[ks], bf, acc0[nt], 0, 0, 0);
                    acc1[nt] = __builtin_amdgcn_mfma_f32_16x16x32_bf16(wA1[ks], bf, acc1[nt], 0, 0, 0);
                }
            }

            float* ob = out + (size_t)(b * 128 + wv * 32) * NPOS + n0;
            #pragma unroll
            for (int nt = 0; nt < 4; ++nt) {
                #pragma unroll
                for (int r = 0; r < 4; ++r) {
                    ob[(     lg * 4 + r) * NPOS + nt * 16 + l15] = acc0[nt][r];
                    ob[(16 + lg * 4 + r) * NPOS + nt * 16 + l15] = acc1[nt][r];
                }
            }
        }
        // next iteration's post-A barrier separates this C (F reads) from next B (F writes)
    }
}

extern "C" void kernel_launch(void* const* d_in, const int* in_sizes, int n_in,
                              void* d_out, int out_size, void* d_ws, size_t ws_size,
                              hipStream_t stream) {
    const float* img   = (const float*)d_in[0];
    const float* pixT  = (const float*)d_in[1];
    const float* convw = (const float*)d_in[2];
    const float* convb = (const float*)d_in[3];
    float* out = (float*)d_out;

    unsigned short* imgT = (unsigned short*)d_ws;             // 262144 bf16 = 512 KiB
    unsigned short* Wp   = imgT + 262144;                     // 65536 bf16 = 128 KiB

    hipLaunchKernelGGL(bili_prep, dim3(1280), dim3(256), 0, stream,
                       img, convw, imgT, Wp);
    hipLaunchKernelGGL(bili_main, dim3(512), dim3(256), 0, stream,
                       (const uint4*)imgT, Wp, pixT, convb, out);
}

// Round 5
// 44.194 us; speedup vs baseline: 1.4997x; 1.4997x over previous
//
#include <hip/hip_runtime.h>

// BiliSample fused: bilinear-sample BEV features + 1x1 conv (GEMM) + bias.
// img_feat (2,64,32,64) f32, pix_T_cam (2,3,3) f32, conv_w (128,512) f32,
// conv_b (128,) f32 -> out (2,128,200,200) f32.
//
//  prep:  imgT[b][y][x][c] = bf16(img[b][c][y][x])   (c contiguous)
//         Wp[o][k'=y*64+c] = bf16(conv_w[o][c*8+y])  (k-permuted)
//  main (1250 blocks, 1 tile of 64 n each, 44 KiB LDS, software-pipelined):
//    A: 512 (n,y) projections -> packed u16 offsets + f32 weights in LDS
//    4 k-quarter phases (y-pairs), F double-buffered 2x16 KiB:
//      phase q: {issue 16 sample loads (q)} {8 W loads + MFMA quarter q-1}
//               {bilinear-process q, ds_write Fbuf[q&1]} barrier
//    epilogue: MFMA quarter 3 + stores. Sample L2 latency hides under MFMA.

#define NPOS 40000

typedef short bf16x8 __attribute__((ext_vector_type(8)));
typedef float f32x4  __attribute__((ext_vector_type(4)));

__device__ __forceinline__ unsigned rne16(float f) {
    unsigned u = __float_as_uint(f);
    return (u + 0x7fffu + ((u >> 16) & 1u)) >> 16;
}
__device__ __forceinline__ float lo16(unsigned u) { return __uint_as_float(u << 16); }
__device__ __forceinline__ float hi16(unsigned u) { return __uint_as_float(u & 0xffff0000u); }
__device__ __forceinline__ unsigned cvtpk(float lo, float hi) {
    unsigned r;
    asm("v_cvt_pk_bf16_f32 %0, %1, %2" : "=v"(r) : "v"(lo), "v"(hi));
    return r;
}

// ---------------- prep: transpose img to channel-major bf16, permute W ----------------
__global__ __launch_bounds__(256)
void bili_prep(const float* __restrict__ img, const float* __restrict__ convw,
               unsigned short* __restrict__ imgT, unsigned short* __restrict__ Wp)
{
    const int i = blockIdx.x * 256 + threadIdx.x;
    if (blockIdx.x < 1024) {
        // imgT[b][y][x][c], i = ((b*32+y)*64+x)*64+c
        const int c = i & 63, x = (i >> 6) & 63, y = (i >> 12) & 31, b = i >> 17;
        imgT[i] = (unsigned short)rne16(img[((b * 64 + c) * 32 + y) * 64 + x]);
    } else {
        const int j = i - 1024 * 256;            // 0..65535
        const int k = j & 511, o = j >> 9;
        const int y = k >> 6, c = k & 63;
        Wp[j] = (unsigned short)rne16(convw[o * 512 + c * 8 + y]);
    }
}

// ---------------- main fused pipelined kernel ----------------
__global__ __launch_bounds__(256, 2)
void bili_main(const uint4* __restrict__ imgTq,     // per-batch stride 16384 uint4
               const unsigned short* __restrict__ Wp,
               const float* __restrict__ pixT,
               const float* __restrict__ convb,
               float* __restrict__ out)
{
    __shared__ uint4  Fb[2][1024];   // two k-quarter buffers [64 n][16 uint4], swizzled
    __shared__ uint2  offsC[512];    // per (n,y): 4 corner offsets packed 4 x u16
    __shared__ float4 wtsL[512];     // per (n,y): 4 corner weights (f32)

    const int t   = threadIdx.x;
    const int bx  = blockIdx.x;
    const int b   = (bx >= 625) ? 1 : 0;
    const int n0  = (bx - b * 625) * 64;

    const int wv  = t >> 6;          // wave 0..3 -> o rows wv*32..+31
    const int ln  = t & 63;
    const int l15 = ln & 15;
    const int lg  = ln >> 4;         // k-slot group
    const int g   = t >> 3;          // sample group 0..31
    const int li  = t & 7;           // lane-in-group: channel block

    // ---------- bias preload + acc init ----------
    float bias0[4], bias1[4];
    #pragma unroll
    for (int r = 0; r < 4; ++r) {
        bias0[r] = convb[wv * 32 +      lg * 4 + r];
        bias1[r] = convb[wv * 32 + 16 + lg * 4 + r];
    }
    f32x4 acc0[4], acc1[4];
    #pragma unroll
    for (int nt = 0; nt < 4; ++nt)
        #pragma unroll
        for (int r = 0; r < 4; ++r) { acc0[nt][r] = bias0[r]; acc1[nt][r] = bias1[r]; }

    // ---------- phase A: projections (2 per thread) ----------
    {
        const float* Kb = pixT + b * 9;
        const float K00 = Kb[0], K01 = Kb[1], K02 = Kb[2];
        const float K10 = Kb[3], K11 = Kb[4], K12 = Kb[5];
        const float K20 = Kb[6], K21 = Kb[7], K22 = Kb[8];

        #pragma unroll
        for (int r = 0; r < 2; ++r) {
            const int p    = r * 256 + t;        // 0..511
            const int nloc = p >> 3;
            const int y    = p & 7;
            const int n = n0 + nloc;
            const int z = n / 200;
            const int x = n - z * 200;

            const float pxv = (x * (1.0f / 199.0f) - 0.5f) * 80.0f;
            const float pzv = (z * (1.0f / 199.0f)) * 80.0f;
            const float pyv = (y * (1.0f / 7.0f) - 0.5f) * 6.0f;

            const float p0 = K00 * pxv + K01 * pyv + K02 * pzv;
            const float p1 = K10 * pxv + K11 * pyv + K12 * pzv;
            const float d  = K20 * pxv + K21 * pyv + K22 * pzv;
            const float dpe = d + 1e-8f;
            const float u01 = p0 / dpe / 512.0f;
            const float v01 = p1 / dpe / 256.0f;
            const float vf = (u01 >= 0.0f && u01 <= 1.0f &&
                              v01 >= 0.0f && v01 <= 1.0f) ? 1.0f : 0.0f;

            float xp = u01 * 64.0f - 0.5f;
            xp = fminf(fmaxf(xp, -2.0f), 66.0f);
            const float x0f = floorf(xp);
            const float wx = xp - x0f;
            const int x0 = (int)x0f, x1i = x0 + 1;
            const float wx0 = (1.0f - wx) * vf * ((x0  >= 0 && x0  < 64) ? 1.0f : 0.0f);
            const float wx1 = wx          * vf * ((x1i >= 0 && x1i < 64) ? 1.0f : 0.0f);
            const int xi0 = min(max(x0, 0), 63);
            const int xi1 = min(max(x1i, 0), 63);

            float yp = v01 * 32.0f - 0.5f;
            yp = fminf(fmaxf(yp, -2.0f), 34.0f);
            const float y0f = floorf(yp);
            const float wy = yp - y0f;
            const int y0 = (int)y0f, y1i = y0 + 1;
            const float wy0 = (1.0f - wy) * ((y0  >= 0 && y0  < 32) ? 1.0f : 0.0f);
            const float wy1 = wy          * ((y1i >= 0 && y1i < 32) ? 1.0f : 0.0f);
            const int yi0 = min(max(y0, 0), 31);
            const int yi1 = min(max(y1i, 0), 31);

            const unsigned o0 = (unsigned)(((yi0 << 6) + xi0) << 3);
            const unsigned o1 = (unsigned)(((yi0 << 6) + xi1) << 3);
            const unsigned o2 = (unsigned)(((yi1 << 6) + xi0) << 3);
            const unsigned o3 = (unsigned)(((yi1 << 6) + xi1) << 3);

            wtsL[p]  = make_float4(wx0 * wy0, wx1 * wy0, wx0 * wy1, wx1 * wy1);
            offsC[p] = make_uint2(o0 | (o1 << 16), o2 | (o3 << 16));
        }
    }

    __syncthreads();

    const uint4*  imgTb = imgTq + b * 16384;
    const bf16x8* ApG   = (const bf16x8*)Wp;           // [128 rows][64 slots]
    const bf16x8* Ap0   = ApG + ((wv * 32 +      l15) * 64 + lg);
    const bf16x8* Ap1   = ApG + ((wv * 32 + 16 + l15) * 64 + lg);

    uint4  sbuf[16];
    float4 wreg[4];

    // issue quarter-q sample loads (16 uint4 in flight) + stash weights
    #define ISSUE(q)                                                           \
        _Pragma("unroll")                                                      \
        for (int it = 0; it < 4; ++it) {                                       \
            const int pp = it * 32 + g;                                        \
            const int n_ = pp >> 1, ys = pp & 1;                               \
            const int p_ = n_ * 8 + 2 * (q) + ys;                              \
            const uint2 oc = offsC[p_];                                        \
            wreg[it] = wtsL[p_];                                               \
            sbuf[it * 4 + 0] = imgTb[(oc.x & 0xffffu) + li];                   \
            sbuf[it * 4 + 1] = imgTb[(oc.x >> 16)     + li];                   \
            sbuf[it * 4 + 2] = imgTb[(oc.y & 0xffffu) + li];                   \
            sbuf[it * 4 + 3] = imgTb[(oc.y >> 16)     + li];                   \
        }

    // MFMA one k-quarter (q) out of buf; W loads are L1/L2-hot
    #define MFMAQ(q, buf)                                                      \
        do {                                                                   \
            bf16x8 a0_[4], a1_[4];                                             \
            _Pragma("unroll")                                                  \
            for (int k = 0; k < 4; ++k) {                                      \
                a0_[k] = Ap0[((q) * 4 + k) * 4];                               \
                a1_[k] = Ap1[((q) * 4 + k) * 4];                               \
            }                                                                  \
            const bf16x8* Fv = (const bf16x8*)(buf);                           \
            _Pragma("unroll")                                                  \
            for (int k = 0; k < 4; ++k) {                                      \
                _Pragma("unroll")                                              \
                for (int nt = 0; nt < 4; ++nt) {                               \
                    const int nn = nt * 16 + l15;                              \
                    const bf16x8 bv = Fv[nn * 16 + ((k * 4 + lg) ^ (nn & 7))]; \
                    acc0[nt] = __builtin_amdgcn_mfma_f32_16x16x32_bf16(a0_[k], bv, acc0[nt], 0, 0, 0); \
                    acc1[nt] = __builtin_amdgcn_mfma_f32_16x16x32_bf16(a1_[k], bv, acc1[nt], 0, 0, 0); \
                }                                                              \
            }                                                                  \
        } while (0)

    // bilinear-combine quarter q's samples, pack bf16, write to buf
    #define PROCESS(q, buf)                                                    \
        _Pragma("unroll")                                                      \
        for (int it = 0; it < 4; ++it) {                                       \
            const int pp = it * 32 + g;                                        \
            const int n_ = pp >> 1, ys = pp & 1;                               \
            const float4 w = wreg[it];                                         \
            float2 ac[4];                                                      \
            _Pragma("unroll")                                                  \
            for (int qq = 0; qq < 4; ++qq) ac[qq] = make_float2(0.0f, 0.0f);   \
            _Pragma("unroll")                                                  \
            for (int j = 0; j < 4; ++j) {                                      \
                const uint4 v = sbuf[it * 4 + j];                              \
                const float ww = (j == 0) ? w.x : (j == 1) ? w.y : (j == 2) ? w.z : w.w; \
                ac[0].x = fmaf(ww, lo16(v.x), ac[0].x);                        \
                ac[0].y = fmaf(ww, hi16(v.x), ac[0].y);                        \
                ac[1].x = fmaf(ww, lo16(v.y), ac[1].x);                        \
                ac[1].y = fmaf(ww, hi16(v.y), ac[1].y);                        \
                ac[2].x = fmaf(ww, lo16(v.z), ac[2].x);                        \
                ac[2].y = fmaf(ww, hi16(v.z), ac[2].y);                        \
                ac[3].x = fmaf(ww, lo16(v.w), ac[3].x);                        \
                ac[3].y = fmaf(ww, hi16(v.w), ac[3].y);                        \
            }                                                                  \
            uint4 pk;                                                          \
            pk.x = cvtpk(ac[0].x, ac[0].y);                                    \
            pk.y = cvtpk(ac[1].x, ac[1].y);                                    \
            pk.z = cvtpk(ac[2].x, ac[2].y);                                    \
            pk.w = cvtpk(ac[3].x, ac[3].y);                                    \
            (buf)[n_ * 16 + ((ys * 8 + li) ^ (n_ & 7))] = pk;                  \
        }

    // ---------- pipelined quarters ----------
    ISSUE(0);                 PROCESS(0, Fb[0]); __syncthreads();
    ISSUE(1); MFMAQ(0, Fb[0]); PROCESS(1, Fb[1]); __syncthreads();
    ISSUE(2); MFMAQ(1, Fb[1]); PROCESS(2, Fb[0]); __syncthreads();
    ISSUE(3); MFMAQ(2, Fb[0]); PROCESS(3, Fb[1]); __syncthreads();
    MFMAQ(3, Fb[1]);

    #undef ISSUE
    #undef MFMAQ
    #undef PROCESS

    // ---------- stores ----------
    {
        float* ob = out + (size_t)(b * 128 + wv * 32) * NPOS + n0;
        #pragma unroll
        for (int nt = 0; nt < 4; ++nt) {
            #pragma unroll
            for (int r = 0; r < 4; ++r) {
                ob[(     lg * 4 + r) * NPOS + nt * 16 + l15] = acc0[nt][r];
                ob[(16 + lg * 4 + r) * NPOS + nt * 16 + l15] = acc1[nt][r];
            }
        }
    }
}

extern "C" void kernel_launch(void* const* d_in, const int* in_sizes, int n_in,
                              void* d_out, int out_size, void* d_ws, size_t ws_size,
                              hipStream_t stream) {
    const float* img   = (const float*)d_in[0];
    const float* pixT  = (const float*)d_in[1];
    const float* convw = (const float*)d_in[2];
    const float* convb = (const float*)d_in[3];
    float* out = (float*)d_out;

    unsigned short* imgT = (unsigned short*)d_ws;             // 262144 bf16 = 512 KiB
    unsigned short* Wp   = imgT + 262144;                     // 65536 bf16 = 128 KiB

    hipLaunchKernelGGL(bili_prep, dim3(1280), dim3(256), 0, stream,
                       img, convw, imgT, Wp);
    hipLaunchKernelGGL(bili_main, dim3(1250), dim3(256), 0, stream,
                       (const uint4*)imgT, Wp, pixT, convb, out);
}

// Round 6
// 43.557 us; speedup vs baseline: 1.5216x; 1.0146x over previous
//
#include <hip/hip_runtime.h>

// BiliSample fused: bilinear-sample BEV features + 1x1 conv (GEMM) + bias.
// img_feat (2,64,32,64) f32, pix_T_cam (2,3,3) f32, conv_w (128,512) f32,
// conv_b (128,) f32 -> out (2,128,200,200) f32.
//
//  prep:  imgT[b][y][x][c] = bf16(img[b][c][y][x])   (c contiguous)
//         Wp[o][k'=y*64+c] = bf16(conv_w[o][c*8+y])  (k-permuted)
//  main (1250 blocks, 64-n tile, 44 KiB LDS, depth-2 half-quarter pipeline):
//    A: 512 (n,y) projections (rcp fast-path) -> packed offsets + weights LDS
//    8 half-quarters, sbE/sbO alternate (8 uint4 in flight each), F quarters
//    double-buffered; each PROC consumes loads issued ~2 slots earlier with
//    MFMA halves + a barrier in between -> gather latency hidden.

#define NPOS 40000

typedef short bf16x8 __attribute__((ext_vector_type(8)));
typedef float f32x4  __attribute__((ext_vector_type(4)));

__device__ __forceinline__ unsigned rne16(float f) {
    unsigned u = __float_as_uint(f);
    return (u + 0x7fffu + ((u >> 16) & 1u)) >> 16;
}
__device__ __forceinline__ float lo16(unsigned u) { return __uint_as_float(u << 16); }
__device__ __forceinline__ float hi16(unsigned u) { return __uint_as_float(u & 0xffff0000u); }
__device__ __forceinline__ unsigned cvtpk(float lo, float hi) {
    unsigned r;
    asm("v_cvt_pk_bf16_f32 %0, %1, %2" : "=v"(r) : "v"(lo), "v"(hi));
    return r;
}

// ---------------- prep: transpose img to channel-major bf16, permute W ----------------
__global__ __launch_bounds__(256)
void bili_prep(const float* __restrict__ img, const float* __restrict__ convw,
               unsigned short* __restrict__ imgT, unsigned short* __restrict__ Wp)
{
    const int i = blockIdx.x * 256 + threadIdx.x;
    if (blockIdx.x < 1024) {
        // imgT[b][y][x][c], i = ((b*32+y)*64+x)*64+c
        const int c = i & 63, x = (i >> 6) & 63, y = (i >> 12) & 31, b = i >> 17;
        imgT[i] = (unsigned short)rne16(img[((b * 64 + c) * 32 + y) * 64 + x]);
    } else {
        const int j = i - 1024 * 256;            // 0..65535
        const int k = j & 511, o = j >> 9;
        const int y = k >> 6, c = k & 63;
        Wp[j] = (unsigned short)rne16(convw[o * 512 + c * 8 + y]);
    }
}

// ---------------- main fused pipelined kernel ----------------
__global__ __launch_bounds__(256, 3)
void bili_main(const uint4* __restrict__ imgTq,     // per-batch stride 16384 uint4
               const unsigned short* __restrict__ Wp,
               const float* __restrict__ pixT,
               const float* __restrict__ convb,
               float* __restrict__ out)
{
    __shared__ uint4  Fb[2][1024];   // two k-quarter buffers [64 n][16 uint4], swizzled
    __shared__ uint2  offsC[512];    // per (n,y): 4 corner offsets packed 4 x u16
    __shared__ float4 wtsL[512];     // per (n,y): 4 corner weights (f32)

    const int t   = threadIdx.x;
    const int bx  = blockIdx.x;
    const int b   = (bx >= 625) ? 1 : 0;
    const int n0  = (bx - b * 625) * 64;

    const int wv  = t >> 6;          // wave 0..3 -> o rows wv*32..+31
    const int ln  = t & 63;
    const int l15 = ln & 15;
    const int lg  = ln >> 4;         // k-slot group
    const int g   = t >> 3;          // sample group 0..31
    const int li  = t & 7;           // lane-in-group: channel block

    // ---------- bias preload + acc init ----------
    f32x4 acc0[4], acc1[4];
    {
        float bias0[4], bias1[4];
        #pragma unroll
        for (int r = 0; r < 4; ++r) {
            bias0[r] = convb[wv * 32 +      lg * 4 + r];
            bias1[r] = convb[wv * 32 + 16 + lg * 4 + r];
        }
        #pragma unroll
        for (int nt = 0; nt < 4; ++nt)
            #pragma unroll
            for (int r = 0; r < 4; ++r) { acc0[nt][r] = bias0[r]; acc1[nt][r] = bias1[r]; }
    }

    // ---------- phase A: projections (2 per thread, fast rcp) ----------
    {
        const float* Kb = pixT + b * 9;
        const float K00 = Kb[0], K01 = Kb[1], K02 = Kb[2];
        const float K10 = Kb[3], K11 = Kb[4], K12 = Kb[5];
        const float K20 = Kb[6], K21 = Kb[7], K22 = Kb[8];

        #pragma unroll
        for (int r = 0; r < 2; ++r) {
            const int p    = r * 256 + t;        // 0..511
            const int nloc = p >> 3;
            const int y    = p & 7;
            const int n = n0 + nloc;
            const int z = n / 200;
            const int x = n - z * 200;

            const float pxv = (x * (1.0f / 199.0f) - 0.5f) * 80.0f;
            const float pzv = (z * (1.0f / 199.0f)) * 80.0f;
            const float pyv = (y * (1.0f / 7.0f) - 0.5f) * 6.0f;

            const float p0 = K00 * pxv + K01 * pyv + K02 * pzv;
            const float p1 = K10 * pxv + K11 * pyv + K12 * pzv;
            const float d  = K20 * pxv + K21 * pyv + K22 * pzv;
            const float inv = __builtin_amdgcn_rcpf(d + 1e-8f);
            const float u01 = p0 * inv * (1.0f / 512.0f);
            const float v01 = p1 * inv * (1.0f / 256.0f);
            const float vf = (u01 >= 0.0f && u01 <= 1.0f &&
                              v01 >= 0.0f && v01 <= 1.0f) ? 1.0f : 0.0f;

            float xp = u01 * 64.0f - 0.5f;
            xp = fminf(fmaxf(xp, -2.0f), 66.0f);
            const float x0f = floorf(xp);
            const float wx = xp - x0f;
            const int x0 = (int)x0f, x1i = x0 + 1;
            const float wx0 = (1.0f - wx) * vf * ((x0  >= 0 && x0  < 64) ? 1.0f : 0.0f);
            const float wx1 = wx          * vf * ((x1i >= 0 && x1i < 64) ? 1.0f : 0.0f);
            const int xi0 = min(max(x0, 0), 63);
            const int xi1 = min(max(x1i, 0), 63);

            float yp = v01 * 32.0f - 0.5f;
            yp = fminf(fmaxf(yp, -2.0f), 34.0f);
            const float y0f = floorf(yp);
            const float wy = yp - y0f;
            const int y0 = (int)y0f, y1i = y0 + 1;
            const float wy0 = (1.0f - wy) * ((y0  >= 0 && y0  < 32) ? 1.0f : 0.0f);
            const float wy1 = wy          * ((y1i >= 0 && y1i < 32) ? 1.0f : 0.0f);
            const int yi0 = min(max(y0, 0), 31);
            const int yi1 = min(max(y1i, 0), 31);

            const unsigned o0 = (unsigned)(((yi0 << 6) + xi0) << 3);
            const unsigned o1 = (unsigned)(((yi0 << 6) + xi1) << 3);
            const unsigned o2 = (unsigned)(((yi1 << 6) + xi0) << 3);
            const unsigned o3 = (unsigned)(((yi1 << 6) + xi1) << 3);

            wtsL[p]  = make_float4(wx0 * wy0, wx1 * wy0, wx0 * wy1, wx1 * wy1);
            offsC[p] = make_uint2(o0 | (o1 << 16), o2 | (o3 << 16));
        }
    }

    __syncthreads();

    const uint4*  imgTb = imgTq + b * 16384;
    const bf16x8* ApG   = (const bf16x8*)Wp;           // [128 rows][64 slots]
    const bf16x8* Ap0   = ApG + ((wv * 32 +      l15) * 64 + lg);
    const bf16x8* Ap1   = ApG + ((wv * 32 + 16 + l15) * 64 + lg);

    uint4 sbE[8], sbO[8];

    // issue half-quarter (q, half hb): 8 uint4 loads into SB
    #define ISSUE_H(q, hb, SB)                                                 \
        _Pragma("unroll")                                                      \
        for (int it2 = 0; it2 < 2; ++it2) {                                    \
            const int pp = ((hb) * 2 + it2) * 32 + g;                          \
            const int n_ = pp >> 1, ys = pp & 1;                               \
            const int p_ = n_ * 8 + 2 * (q) + ys;                              \
            const uint2 oc = offsC[p_];                                        \
            SB[it2 * 4 + 0] = imgTb[(oc.x & 0xffffu) + li];                    \
            SB[it2 * 4 + 1] = imgTb[(oc.x >> 16)     + li];                    \
            SB[it2 * 4 + 2] = imgTb[(oc.y & 0xffffu) + li];                    \
            SB[it2 * 4 + 3] = imgTb[(oc.y >> 16)     + li];                    \
        }

    // bilinear-combine half-quarter, pack bf16, write F buffer
    #define PROC_H(q, hb, SB, buf)                                             \
        _Pragma("unroll")                                                      \
        for (int it2 = 0; it2 < 2; ++it2) {                                    \
            const int pp = ((hb) * 2 + it2) * 32 + g;                          \
            const int n_ = pp >> 1, ys = pp & 1;                               \
            const int p_ = n_ * 8 + 2 * (q) + ys;                              \
            const float4 w = wtsL[p_];                                         \
            float2 ac[4];                                                      \
            _Pragma("unroll")                                                  \
            for (int qq = 0; qq < 4; ++qq) ac[qq] = make_float2(0.0f, 0.0f);   \
            _Pragma("unroll")                                                  \
            for (int j = 0; j < 4; ++j) {                                      \
                const uint4 v = SB[it2 * 4 + j];                               \
                const float ww = (j == 0) ? w.x : (j == 1) ? w.y : (j == 2) ? w.z : w.w; \
                ac[0].x = fmaf(ww, lo16(v.x), ac[0].x);                        \
                ac[0].y = fmaf(ww, hi16(v.x), ac[0].y);                        \
                ac[1].x = fmaf(ww, lo16(v.y), ac[1].x);                        \
                ac[1].y = fmaf(ww, hi16(v.y), ac[1].y);                        \
                ac[2].x = fmaf(ww, lo16(v.z), ac[2].x);                        \
                ac[2].y = fmaf(ww, hi16(v.z), ac[2].y);                        \
                ac[3].x = fmaf(ww, lo16(v.w), ac[3].x);                        \
                ac[3].y = fmaf(ww, hi16(v.w), ac[3].y);                        \
            }                                                                  \
            uint4 pk;                                                          \
            pk.x = cvtpk(ac[0].x, ac[0].y);                                    \
            pk.y = cvtpk(ac[1].x, ac[1].y);                                    \
            pk.z = cvtpk(ac[2].x, ac[2].y);                                    \
            pk.w = cvtpk(ac[3].x, ac[3].y);                                    \
            (buf)[n_ * 16 + ((ys * 8 + li) ^ (n_ & 7))] = pk;                  \
        }

    // MFMA half (k pair) of quarter q out of buf; W loads L1/L2-hot
    #define MFMA_H(q, hf, buf)                                                 \
        do {                                                                   \
            const bf16x8* Fv = (const bf16x8*)(buf);                           \
            _Pragma("unroll")                                                  \
            for (int k2 = 0; k2 < 2; ++k2) {                                   \
                const int k = (hf) * 2 + k2;                                   \
                const bf16x8 a0_ = Ap0[((q) * 4 + k) * 4];                     \
                const bf16x8 a1_ = Ap1[((q) * 4 + k) * 4];                     \
                _Pragma("unroll")                                              \
                for (int nt = 0; nt < 4; ++nt) {                               \
                    const int nn = nt * 16 + l15;                              \
                    const bf16x8 bv = Fv[nn * 16 + ((k * 4 + lg) ^ (nn & 7))]; \
                    acc0[nt] = __builtin_amdgcn_mfma_f32_16x16x32_bf16(a0_, bv, acc0[nt], 0, 0, 0); \
                    acc1[nt] = __builtin_amdgcn_mfma_f32_16x16x32_bf16(a1_, bv, acc1[nt], 0, 0, 0); \
                }                                                              \
            }                                                                  \
        } while (0)

    // ---------- depth-2 half-quarter pipeline ----------
    ISSUE_H(0, 0, sbE);
    ISSUE_H(0, 1, sbO);
    PROC_H (0, 0, sbE, Fb[0]);
    ISSUE_H(1, 0, sbE);
    PROC_H (0, 1, sbO, Fb[0]);
    __syncthreads();

    ISSUE_H(1, 1, sbO);
    MFMA_H (0, 0, Fb[0]);
    PROC_H (1, 0, sbE, Fb[1]);
    ISSUE_H(2, 0, sbE);
    MFMA_H (0, 1, Fb[0]);
    PROC_H (1, 1, sbO, Fb[1]);
    __syncthreads();

    ISSUE_H(2, 1, sbO);
    MFMA_H (1, 0, Fb[1]);
    PROC_H (2, 0, sbE, Fb[0]);
    ISSUE_H(3, 0, sbE);
    MFMA_H (1, 1, Fb[1]);
    PROC_H (2, 1, sbO, Fb[0]);
    __syncthreads();

    ISSUE_H(3, 1, sbO);
    MFMA_H (2, 0, Fb[0]);
    PROC_H (3, 0, sbE, Fb[1]);
    MFMA_H (2, 1, Fb[0]);
    PROC_H (3, 1, sbO, Fb[1]);
    __syncthreads();

    MFMA_H (3, 0, Fb[1]);
    MFMA_H (3, 1, Fb[1]);

    #undef ISSUE_H
    #undef PROC_H
    #undef MFMA_H

    // ---------- stores ----------
    {
        float* ob = out + (size_t)(b * 128 + wv * 32) * NPOS + n0;
        #pragma unroll
        for (int nt = 0; nt < 4; ++nt) {
            #pragma unroll
            for (int r = 0; r < 4; ++r) {
                ob[(     lg * 4 + r) * NPOS + nt * 16 + l15] = acc0[nt][r];
                ob[(16 + lg * 4 + r) * NPOS + nt * 16 + l15] = acc1[nt][r];
            }
        }
    }
}

extern "C" void kernel_launch(void* const* d_in, const int* in_sizes, int n_in,
                              void* d_out, int out_size, void* d_ws, size_t ws_size,
                              hipStream_t stream) {
    const float* img   = (const float*)d_in[0];
    const float* pixT  = (const float*)d_in[1];
    const float* convw = (const float*)d_in[2];
    const float* convb = (const float*)d_in[3];
    float* out = (float*)d_out;

    unsigned short* imgT = (unsigned short*)d_ws;             // 262144 bf16 = 512 KiB
    unsigned short* Wp   = imgT + 262144;                     // 65536 bf16 = 128 KiB

    hipLaunchKernelGGL(bili_prep, dim3(1280), dim3(256), 0, stream,
                       img, convw, imgT, Wp);
    hipLaunchKernelGGL(bili_main, dim3(1250), dim3(256), 0, stream,
                       (const uint4*)imgT, Wp, pixT, convb, out);
}